// Round 1
// baseline (504.130 us; speedup 1.0000x reference)
//
#include <hip/hip_runtime.h>
#include <math.h>

#define BS  256
#define SEQ 512
#define H   768

// ---------------- Threefry-2x32-20, key = (0, 42) -- matches JAX exactly ---
__device__ __forceinline__ unsigned rotl32(unsigned x, int r) {
  return (x << r) | (x >> (32 - r));
}

__device__ __forceinline__ void threefry_0_42(unsigned& x0, unsigned& x1) {
  const unsigned ks0 = 0u;
  const unsigned ks1 = 42u;
  const unsigned ks2 = ks0 ^ ks1 ^ 0x1BD11BDAu;
  x0 += ks0; x1 += ks1;
#define TF_ROUND(r) { x0 += x1; x1 = rotl32(x1, (r)); x1 ^= x0; }
  TF_ROUND(13) TF_ROUND(15) TF_ROUND(26) TF_ROUND(6)
  x0 += ks1; x1 += ks2 + 1u;
  TF_ROUND(17) TF_ROUND(29) TF_ROUND(16) TF_ROUND(24)
  x0 += ks2; x1 += ks0 + 2u;
  TF_ROUND(13) TF_ROUND(15) TF_ROUND(26) TF_ROUND(6)
  x0 += ks0; x1 += ks1 + 3u;
  TF_ROUND(17) TF_ROUND(29) TF_ROUND(16) TF_ROUND(24)
  x0 += ks1; x1 += ks2 + 4u;
  TF_ROUND(13) TF_ROUND(15) TF_ROUND(26) TF_ROUND(6)
  x0 += ks2; x1 += ks0 + 5u;
#undef TF_ROUND
}

// ---------------- Kernel 1: length + sample + gather; zero accs/counters --
__global__ __launch_bounds__(256) void prep_kernel(
    const float* __restrict__ tokens,   // [BS, SEQ, H]
    const int*   __restrict__ mask,     // [BS, SEQ]
    float* __restrict__ emb,            // [BS, H] out (ws)
    float* __restrict__ ge0,            // [BS] zeroed
    float* __restrict__ ge1,            // [BS] zeroed
    int*   __restrict__ cnt)            // [8] zeroed (per-m-tile arrival cnt)
{
  const int b = blockIdx.x;
  const int t = threadIdx.x;

  if (t == 0) { ge0[b] = 0.0f; ge1[b] = 0.0f; }
  if (b == 0 && t < 8) cnt[t] = 0;

  // length = number of LEADING ones == first zero position (SEQ if none).
  // Shuffle-min tree (deterministic, no serialized LDS atomics).
  int cand = SEQ;
  if (mask[b * SEQ + t] == 0)       cand = t;
  if (mask[b * SEQ + t + 256] == 0) cand = min(cand, t + 256);
#pragma unroll
  for (int off = 32; off > 0; off >>= 1)
    cand = min(cand, __shfl_xor(cand, off));
  __shared__ int s_w[4];
  if ((t & 63) == 0) s_w[t >> 6] = cand;
  __syncthreads();
  const int len = min(min(s_w[0], s_w[1]), min(s_w[2], s_w[3]));
  const float lenf = (float)len;

#pragma unroll
  for (int p = 0; p < 3; ++p) {
    const int j = t + 256 * p;
    const unsigned n = (unsigned)(b * H + j);
    unsigned x0 = 0u, x1 = n;
    threefry_0_42(x0, x1);
    const unsigned bits = x0 ^ x1;
    const float u = __uint_as_float((bits >> 9) | 0x3f800000u) - 1.0f;
    int idx = (int)floorf(u * lenf);
    idx = min(idx, len - 1);
    emb[n] = tokens[(size_t)b * (SEQ * H) + (size_t)idx * H + j];
  }
}

// ---------------- Kernel 2: tiled triple-GEMM + tanh-energy + fused blend --
// T = cls@Wtop, U0 = cls@Wbot, U1 = emb@Wbot per 32x32 tile in one k-loop;
// e0_partial[b] += sum_n v*tanh(T+U0+bias), e1 likewise, via atomicAdd.
// The LAST n-block of each m-tile (device-scope counter) then applies
// softmax(2) and writes out = a0*cls + a1*emb for its 32 rows.
#define TM 32
#define TN 32
#define BKK 32
#define PAD 2
__global__ __launch_bounds__(256) void gemm_fused_kernel(
    const float* __restrict__ cls,      // [BS, H]
    const float* __restrict__ emb,      // [BS, H] (ws)
    const float* __restrict__ W,        // [2H, H]
    const float* __restrict__ bias,     // [H]
    const float* __restrict__ v,        // [H]
    float* __restrict__ ge0,            // [BS]
    float* __restrict__ ge1,            // [BS]
    int*   __restrict__ cnt,            // [8]
    float* __restrict__ out)            // [BS, H]
{
  __shared__ float s_c [BKK][TM + PAD];
  __shared__ float s_e [BKK][TM + PAD];
  __shared__ float s_wt[BKK][TN + PAD];
  __shared__ float s_wb[BKK][TN + PAD];

  const int n0 = blockIdx.x * TN;       // column tile (hidden out)
  const int m0 = blockIdx.y * TM;       // batch tile
  const int t  = threadIdx.x;
  const int tx = t & 15;                // 2 cols each
  const int ty = t >> 4;                // 2 rows each

  const float* __restrict__ Wt = W;
  const float* __restrict__ Wb = W + (size_t)H * H;

  float aT[2][2] = {};
  float a0[2][2] = {};
  float a1[2][2] = {};

  const int lk = t & 31, lr = t >> 5;   // staging: 8 rows per pass

  for (int kk = 0; kk < H; kk += BKK) {
#pragma unroll
    for (int p = 0; p < 4; ++p) {
      const int r = lr + 8 * p;
      s_c[lk][r]  = cls[(size_t)(m0 + r) * H + kk + lk];
      s_e[lk][r]  = emb[(size_t)(m0 + r) * H + kk + lk];
      s_wt[r][lk] = Wt[(size_t)(kk + r) * H + n0 + lk];
      s_wb[r][lk] = Wb[(size_t)(kk + r) * H + n0 + lk];
    }
    __syncthreads();
#pragma unroll
    for (int k = 0; k < BKK; ++k) {
      const float2 c  = *(const float2*)&s_c [k][2 * ty];
      const float2 e  = *(const float2*)&s_e [k][2 * ty];
      const float2 wt = *(const float2*)&s_wt[k][2 * tx];
      const float2 wb = *(const float2*)&s_wb[k][2 * tx];
      aT[0][0] = fmaf(c.x, wt.x, aT[0][0]);
      aT[0][1] = fmaf(c.x, wt.y, aT[0][1]);
      aT[1][0] = fmaf(c.y, wt.x, aT[1][0]);
      aT[1][1] = fmaf(c.y, wt.y, aT[1][1]);
      a0[0][0] = fmaf(c.x, wb.x, a0[0][0]);
      a0[0][1] = fmaf(c.x, wb.y, a0[0][1]);
      a0[1][0] = fmaf(c.y, wb.x, a0[1][0]);
      a0[1][1] = fmaf(c.y, wb.y, a0[1][1]);
      a1[0][0] = fmaf(e.x, wb.x, a1[0][0]);
      a1[0][1] = fmaf(e.x, wb.y, a1[0][1]);
      a1[1][0] = fmaf(e.y, wb.x, a1[1][0]);
      a1[1][1] = fmaf(e.y, wb.y, a1[1][1]);
    }
    __syncthreads();
  }

  // energy partials over this block's 32 columns
  float p0[2] = {0.0f, 0.0f};
  float p1[2] = {0.0f, 0.0f};
#pragma unroll
  for (int j = 0; j < 2; ++j) {
    const int n = n0 + 2 * tx + j;
    const float bb = bias[n];
    const float vv = v[n];
#pragma unroll
    for (int i = 0; i < 2; ++i) {
      p0[i] += vv * tanhf(aT[i][j] + a0[i][j] + bb);
      p1[i] += vv * tanhf(aT[i][j] + a1[i][j] + bb);
    }
  }
  // reduce across the 16 tx lanes (decreasing offsets keep the cone in-group)
#pragma unroll
  for (int off = 8; off > 0; off >>= 1) {
#pragma unroll
    for (int i = 0; i < 2; ++i) {
      p0[i] += __shfl_down(p0[i], off);
      p1[i] += __shfl_down(p1[i], off);
    }
  }
  if (tx == 0) {
#pragma unroll
    for (int i = 0; i < 2; ++i) {
      atomicAdd(&ge0[m0 + 2 * ty + i], p0[i]);
      atomicAdd(&ge1[m0 + 2 * ty + i], p1[i]);
    }
    __threadfence();   // make this thread's energy atomics device-visible
  }
  __syncthreads();

  // last-arriver of the 24 n-blocks for this m-tile does the blend
  __shared__ int s_last;
  if (t == 0) s_last = atomicAdd(&cnt[blockIdx.y], 1);
  __syncthreads();
  if (s_last != (H / TN) - 1) return;   // 23 == last

  __shared__ float s_a0v[TM], s_a1v[TM];
  if (t < TM) {
    // atomic reads from the device-coherent point (all adds are visible:
    // every contributor fenced before bumping the counter)
    const float e0 = atomicAdd(&ge0[m0 + t], 0.0f);
    const float e1 = atomicAdd(&ge1[m0 + t], 0.0f);
    const float mx = fmaxf(e0, e1);
    const float x0 = expf(e0 - mx), x1 = expf(e1 - mx);
    const float inv = 1.0f / (x0 + x1);
    s_a0v[t] = x0 * inv;
    s_a1v[t] = x1 * inv;
  }
  __syncthreads();

  // blend 32 rows x 768 cols with float4: 32*192 = 6144 quads, 24/thread
  for (int q = t; q < TM * (H / 4); q += 256) {
    const int r  = q / (H / 4);
    const int c4 = q - r * (H / 4);
    const size_t base = (size_t)(m0 + r) * H + 4 * c4;
    const float4 cv = *(const float4*)&cls[base];
    const float4 ev = *(const float4*)&emb[base];
    const float a0r = s_a0v[r], a1r = s_a1v[r];
    float4 o;
    o.x = a0r * cv.x + a1r * ev.x;
    o.y = a0r * cv.y + a1r * ev.y;
    o.z = a0r * cv.z + a1r * ev.z;
    o.w = a0r * cv.w + a1r * ev.w;
    *(float4*)&out[base] = o;
  }
}

// ---------------------------------------------------------------------------
extern "C" void kernel_launch(void* const* d_in, const int* in_sizes, int n_in,
                              void* d_out, int out_size, void* d_ws, size_t ws_size,
                              hipStream_t stream) {
  const float* tokens = (const float*)d_in[0];   // [256,512,768] f32
  const float* cls    = (const float*)d_in[1];   // [256,768] f32
  const int*   mask   = (const int*)  d_in[2];   // [256,512] i32
  const float* W      = (const float*)d_in[3];   // [1536,768] f32
  const float* bias   = (const float*)d_in[4];   // [768] f32
  const float* v      = (const float*)d_in[5];   // [768] f32
  float* out = (float*)d_out;

  float* ws  = (float*)d_ws;
  float* emb = ws;                 // BS*H floats (786 KB)
  float* ge0 = ws + BS * H;        // BS floats
  float* ge1 = ge0 + BS;           // BS floats
  int*   cnt = (int*)(ge1 + BS);   // 8 ints (per-m-tile arrival counters)

  prep_kernel<<<BS, 256, 0, stream>>>(tokens, mask, emb, ge0, ge1, cnt);

  dim3 g(H / TN, BS / TM);         // 24 x 8 = 192 blocks
  gemm_fused_kernel<<<g, 256, 0, stream>>>(cls, emb, W, bias, v, ge0, ge1, cnt, out);
}